// Round 10
// baseline (82.078 us; speedup 1.0000x reference)
//
#include <hip/hip_runtime.h>
#include <stdint.h>

// Bitnet int8 x int2 GEMM: C[M,N](i32) = A[M,K](i8) . W[N,K]^T
// Round 10: 1376 blocks x 2 waves, block tile 64(rows)x128(cols), waves
// column-split (each 64x64, acc=64 AGPR). Full K per wave (no K-split).
// Wave-private 4-slot LDS ring staged 3 ahead via global_load_lds, counted
// per-wave vmcnt, ZERO barriers in the entire kernel.

#define MM 1024
#define NN 11008
#define KK 4096
#define MTILES 8
#define NTILES 86
#define NBLOCKS (16 * NTILES)              // 1376 = 16 row-strips x 86 col-tiles
#define STRIDE_A ((size_t)MTILES * 8192)   // A2 bytes per kstep
#define STRIDE_B ((size_t)NTILES * 2048)   // B3 bytes per kstep

using i32x4  = __attribute__((ext_vector_type(4))) int;
using i32x16 = __attribute__((ext_vector_type(16))) int;

__device__ __forceinline__ int pack4(i32x4 v) {
    return (int)(((uint32_t)v[0] & 0xFFu) | (((uint32_t)v[1] & 0xFFu) << 8)
               | (((uint32_t)v[2] & 0xFFu) << 16) | (((uint32_t)v[3] & 0xFFu) << 24));
}

// Fused prepass. Blocks [0,1024): A; [1024,3776): B.
// A2: [kstep][mtile][c]*16B, c = row32*128 + kk2*64 + lane;
//     data: row = mtile*128 + row32*32 + (lane&31), kbyte = kstep*64 + kk2*32
//     + (lane>>5)*16.  => 64-row strip wm is a contiguous 4 KB at wm*4096,
//     internally [mi][kk2][lane] 1 KB chunks.
// B3: [kstep][ntile][half][lane]*16B, dword q = ni*2+kk2 = packed bytes of row
//     n = ntile*128+half*64+ni*32+(lane&31) at int32 off kstep*16+kk2*8+(lane>>5)*4.
__global__ __launch_bounds__(256) void prep_AB(const int* __restrict__ Asrc,
                                               const int* __restrict__ Bsrc,
                                               uint8_t* __restrict__ A2,
                                               uint8_t* __restrict__ B3) {
    if (blockIdx.x < 1024) {
        const int g = blockIdx.x * 256 + threadIdx.x;    // < 262144
        const int kstep = g >> 12;
        const int rem   = g & 4095;
        const int mtile = rem >> 9;
        const int c     = rem & 511;
        const int row32 = (c >> 7) & 3, kk2 = (c >> 6) & 1;
        const int lane  = c & 63;
        const int row   = mtile * 128 + row32 * 32 + (lane & 31);
        const int kbyte = kstep * 64 + kk2 * 32 + (lane >> 5) * 16;
        const i32x4* s4 = (const i32x4*)(Asrc + (size_t)row * KK + kbyte);
        i32x4 o;
#pragma unroll
        for (int q = 0; q < 4; ++q) o[q] = pack4(s4[q]);
        *(i32x4*)(A2 + (size_t)g * 16) = o;
    } else {
        const int t = (blockIdx.x - 1024) * 256 + threadIdx.x;   // < 704512
        const int n = t >> 6, kstep = t & 63;
        const int ntile = n >> 7, hf = (n >> 6) & 1, ni = (n >> 5) & 1, l31 = n & 31;
        const i32x4* s4 = (const i32x4*)(Bsrc + (size_t)n * (KK / 4) + kstep * 16);
        int w[4];                       // j = kk2*2 + h
#pragma unroll
        for (int j = 0; j < 4; ++j) w[j] = pack4(s4[j]);
        uint8_t* base = B3 + ((size_t)kstep * NTILES + ntile) * 2048 + hf * 1024;
        *(int2*)(base + l31 * 16 + ni * 8)        = make_int2(w[0], w[2]);  // h=0
        *(int2*)(base + (l31 + 32) * 16 + ni * 8) = make_int2(w[1], w[3]);  // h=1
    }
}

#define GLOAD_LDS16(g, l) __builtin_amdgcn_global_load_lds(                    \
        (const __attribute__((address_space(1))) uint32_t*)(g),                \
        (__attribute__((address_space(3))) uint32_t*)(l), 16, 0, 0)

#define MFMA_I8 __builtin_amdgcn_mfma_i32_32x32x32_i8

// Stage K-step (T)+3 into ring slot ((T)+3)&3 (wave-private, 4 KB).
#define STAGE(T) do {                                                          \
    const uint8_t* at_ = gA + (size_t)((T) + 3) * STRIDE_A;                    \
    uint8_t* ls_ = &As[wid][((T) + 3) & 3][0];                                 \
    GLOAD_LDS16(at_,        ls_);                                              \
    GLOAD_LDS16(at_ + 1024, ls_ + 1024);                                       \
    GLOAD_LDS16(at_ + 2048, ls_ + 2048);                                       \
    GLOAD_LDS16(at_ + 3072, ls_ + 3072);                                       \
} while (0)

// Load B for K-step (T) into register buffer BI (one 16B load: 4 dwords,
// q = ni*2+kk2).
#define BLOAD(BI, T) bbuf[BI] = *(const i32x4*)(gB + (size_t)(T) * STRIDE_B)

#define COMP(T, BI) do {                                                       \
    const uint8_t* ab_ = &As[wid][(T) & 3][0];                                 \
    i32x4 a00 = *(const i32x4*)(ab_ + lane * 16);                              \
    i32x4 a01 = *(const i32x4*)(ab_ + 1024 + lane * 16);                       \
    i32x4 a10 = *(const i32x4*)(ab_ + 2048 + lane * 16);                       \
    i32x4 a11 = *(const i32x4*)(ab_ + 3072 + lane * 16);                       \
    _Pragma("unroll")                                                          \
    for (int kk2_ = 0; kk2_ < 2; ++kk2_) {                                     \
        const uint32_t q0_ = (uint32_t)bbuf[BI][kk2_];                         \
        const uint32_t q1_ = (uint32_t)bbuf[BI][2 + kk2_];                     \
        i32x4 b0_, b1_;                                                        \
        _Pragma("unroll")                                                      \
        for (int i_ = 0; i_ < 4; ++i_) {                                       \
            b0_[i_] = (int)((q0_ >> (2 * i_)) & 0x03030303u);                  \
            b1_[i_] = (int)((q1_ >> (2 * i_)) & 0x03030303u);                  \
        }                                                                      \
        const i32x4 am0_ = kk2_ ? a01 : a00;                                   \
        const i32x4 am1_ = kk2_ ? a11 : a10;                                   \
        __builtin_amdgcn_s_setprio(1);                                         \
        acc[0][0] = MFMA_I8(am0_, b0_, acc[0][0], 0, 0, 0);                    \
        acc[0][1] = MFMA_I8(am0_, b1_, acc[0][1], 0, 0, 0);                    \
        acc[1][0] = MFMA_I8(am1_, b0_, acc[1][0], 0, 0, 0);                    \
        acc[1][1] = MFMA_I8(am1_, b1_, acc[1][1], 0, 0, 0);                    \
        __builtin_amdgcn_s_setprio(0);                                         \
    }                                                                          \
} while (0)

// Per K-step: issue next A stage + B prefetch, counted per-wave vmcnt wait
// (in-order retirement => A(T) in LDS and B(T) in regs), then compute.
#define ITER(T, BCUR, BNXT, NW, DOSTAGE, DOB) do {                             \
    if (DOSTAGE) STAGE(T);                                                     \
    if (DOB)     BLOAD(BNXT, (T) + 2);                                         \
    asm volatile("s_waitcnt vmcnt(" #NW ")" ::: "memory");                     \
    __builtin_amdgcn_sched_barrier(0);                                         \
    COMP(T, BCUR);                                                             \
} while (0)

__global__ __launch_bounds__(128, 3) void bitnet_gemm(const uint8_t* __restrict__ A2,
                                                      const uint8_t* __restrict__ B3,
                                                      int* __restrict__ C) {
    const int tid  = threadIdx.x;
    const int lane = tid & 63, wid = tid >> 6;   // wid = column half (wc)
    const int l31  = lane & 31, h = lane >> 5;

    // bijective XCD swizzle (1376 = 8*172), wm fastest within an XCD chunk:
    // each XCD keeps all 16 A strips (4 MB) + ~11 B col-tiles (1.4 MB) L2-hot.
    const int bid = blockIdx.x;
    const int l   = (bid & 7) * (NBLOCKS / 8) + (bid >> 3);
    const int wm  = l & 15;      // 64-row strip 0..15
    const int bn  = l >> 4;      // 128-col tile 0..85

    __shared__ __align__(16) uint8_t As[2][4][4096];   // 32 KiB: per-wave rings

    const uint8_t* gA = A2 + (size_t)wm * 4096 + lane * 16;
    const uint8_t* gB = B3 + (size_t)bn * 2048 + wid * 1024 + lane * 16;

    i32x16 acc[2][2] = {};
    i32x4 bbuf[3];

    // prologue: stage steps 0..2 (12 loads), load B(0), B(1)
    STAGE(-3); STAGE(-2); STAGE(-1);
    BLOAD(0, 0); BLOAD(1, 1);

    ITER(0, 0, 2, 6,  1, 1);
    ITER(1, 1, 0, 10, 1, 1);
#pragma unroll 1
    for (int t = 2; t < 59; t += 3) {
        ITER(t,     2, 1, 10, 1, 1);
        ITER(t + 1, 0, 2, 10, 1, 1);
        ITER(t + 2, 1, 0, 10, 1, 1);
    }
    // t = 59..63: stages stop after t=60 (stages step 63), B stops after t=61
    ITER(59, 2, 1, 10, 1, 1);
    ITER(60, 0, 2, 10, 1, 1);
    ITER(61, 1, 0, 6,  0, 1);
    ITER(62, 2, 1, 1,  0, 0);
    ITER(63, 0, 2, 0,  0, 0);

    // C write: col = lane&31, row = (r&3) + 8*(r>>2) + 4*(lane>>5)
    const int brow = wm * 64, bcol = bn * 128 + wid * 64;
#pragma unroll
    for (int mi = 0; mi < 2; ++mi)
#pragma unroll
        for (int nc = 0; nc < 2; ++nc) {
            const int colg = bcol + nc * 32 + l31;
#pragma unroll
            for (int r = 0; r < 16; ++r) {
                const int rowin = (r & 3) + 8 * (r >> 2) + 4 * h;
                const int rowg  = brow + mi * 32 + rowin;
                C[(size_t)rowg * NN + colg] = acc[mi][nc][r];
            }
        }
}

extern "C" void kernel_launch(void* const* d_in, const int* in_sizes, int n_in,
                              void* d_out, int out_size, void* d_ws, size_t ws_size,
                              hipStream_t stream) {
    const int* A32 = (const int*)d_in[0];   // [M,K] int8 values in int32
    const int* B32 = (const int*)d_in[1];   // [N,K/4] packed bytes in int32
    int* C = (int*)d_out;                   // [M,N] int32

    uint8_t* A2 = (uint8_t*)d_ws;                      // 4 MiB
    uint8_t* B3 = A2 + (size_t)MM * KK;                // 10.75 MiB

    prep_AB<<<dim3(1024 + 2752), dim3(256), 0, stream>>>(A32, B32, A2, B3);
    bitnet_gemm<<<dim3(NBLOCKS), dim3(128), 0, stream>>>(A2, B3, C);
}

// Round 11
// 66.018 us; speedup vs baseline: 1.2433x; 1.2433x over previous
//
#include <hip/hip_runtime.h>
#include <stdint.h>

// Bitnet int8 x int2 GEMM: C[M,N](i32) = A[M,K](i8) . W[N,K]^T
// Round 11: R8 structure (128x128 block, 4 waves, shared LDS ring, counted
// vmcnt + barrier) with DOUBLE K-quantum per iteration: 2 K-steps (K=128),
// 16 MFMA per wait+barrier (halves convoy overhead). 3-slot x 16 KB ring.

#define MM 1024
#define NN 11008
#define KK 4096
#define MTILES 8
#define NTILES 86
#define NBLOCKS (MTILES * NTILES)          // 688
#define STRIDE_A ((size_t)MTILES * 8192)   // A2 bytes per kstep (64)
#define STRIDE_B ((size_t)NTILES * 2048)   // B3 bytes per kstep

using i32x4  = __attribute__((ext_vector_type(4))) int;
using i32x16 = __attribute__((ext_vector_type(16))) int;

__device__ __forceinline__ int pack4(i32x4 v) {
    return (int)(((uint32_t)v[0] & 0xFFu) | (((uint32_t)v[1] & 0xFFu) << 8)
               | (((uint32_t)v[2] & 0xFFu) << 16) | (((uint32_t)v[3] & 0xFFu) << 24));
}

// Fused prepass. Blocks [0,1024): A; [1024,3776): B.
// A2: [kstep][mtile][c]*16B, c = row32*128 + kk2*64 + lane;
//     data: row = mtile*128 + row32*32 + (lane&31), kbyte = kstep*64 + kk2*32
//     + (lane>>5)*16.
// B3: [kstep][ntile][half][lane]*16B, dword q = ni*2+kk2 = packed bytes of row
//     n = ntile*128+half*64+ni*32+(lane&31) at int32 off kstep*16+kk2*8+(lane>>5)*4.
__global__ __launch_bounds__(256) void prep_AB(const int* __restrict__ Asrc,
                                               const int* __restrict__ Bsrc,
                                               uint8_t* __restrict__ A2,
                                               uint8_t* __restrict__ B3) {
    if (blockIdx.x < 1024) {
        const int g = blockIdx.x * 256 + threadIdx.x;    // < 262144
        const int kstep = g >> 12;
        const int rem   = g & 4095;
        const int mtile = rem >> 9;
        const int c     = rem & 511;
        const int row32 = (c >> 7) & 3, kk2 = (c >> 6) & 1;
        const int lane  = c & 63;
        const int row   = mtile * 128 + row32 * 32 + (lane & 31);
        const int kbyte = kstep * 64 + kk2 * 32 + (lane >> 5) * 16;
        const i32x4* s4 = (const i32x4*)(Asrc + (size_t)row * KK + kbyte);
        i32x4 o;
#pragma unroll
        for (int q = 0; q < 4; ++q) o[q] = pack4(s4[q]);
        *(i32x4*)(A2 + (size_t)g * 16) = o;
    } else {
        const int t = (blockIdx.x - 1024) * 256 + threadIdx.x;   // < 704512
        const int n = t >> 6, kstep = t & 63;
        const int ntile = n >> 7, hf = (n >> 6) & 1, ni = (n >> 5) & 1, l31 = n & 31;
        const i32x4* s4 = (const i32x4*)(Bsrc + (size_t)n * (KK / 4) + kstep * 16);
        int w[4];                       // j = kk2*2 + h
#pragma unroll
        for (int j = 0; j < 4; ++j) w[j] = pack4(s4[j]);
        uint8_t* base = B3 + ((size_t)kstep * NTILES + ntile) * 2048 + hf * 1024;
        *(int2*)(base + l31 * 16 + ni * 8)        = make_int2(w[0], w[2]);  // h=0
        *(int2*)(base + (l31 + 32) * 16 + ni * 8) = make_int2(w[1], w[3]);  // h=1
    }
}

#define GLOAD_LDS16(g, l) __builtin_amdgcn_global_load_lds(                    \
        (const __attribute__((address_space(1))) uint32_t*)(g),                \
        (__attribute__((address_space(3))) uint32_t*)(l), 16, 0, 0)

#define MFMA_I8 __builtin_amdgcn_mfma_i32_32x32x32_i8

// Stage ksteps 2*(T2), 2*(T2)+1 into slot SL (16 KB). 4 gload_lds per wave.
#define STAGE2(SL, T2) do {                                                    \
    const uint8_t* s0_ = gA + (size_t)(2 * (T2)) * STRIDE_A;                   \
    const uint8_t* s1_ = s0_ + STRIDE_A;                                       \
    uint8_t* l_ = &As[SL][0];                                                  \
    GLOAD_LDS16(s0_,        l_ + wave * 1024);                                 \
    GLOAD_LDS16(s0_ + 4096, l_ + 4096 + wave * 1024);                          \
    GLOAD_LDS16(s1_,        l_ + 8192 + wave * 1024);                          \
    GLOAD_LDS16(s1_ + 4096, l_ + 12288 + wave * 1024);                         \
} while (0)

// Load the B pair for iteration T2 (ksteps 2*T2, 2*T2+1) into buffer BI.
#define BLOAD2(BI, T2) do {                                                    \
    bb0[BI] = *(const i32x4*)(gB + (size_t)(2 * (T2)) * STRIDE_B);             \
    bb1[BI] = *(const i32x4*)(gB + (size_t)(2 * (T2) + 1) * STRIDE_B);         \
} while (0)

// Compute 2 K-steps from slot SL with B pair BI: 16 MFMA, 8 ds_read_b128.
#define COMP2(SL, BI) do {                                                     \
    _Pragma("unroll")                                                          \
    for (int sub_ = 0; sub_ < 2; ++sub_) {                                     \
        const uint8_t* ab_ = &As[SL][sub_ * 8192];                             \
        const i32x4 bv_ = sub_ ? bb1[BI] : bb0[BI];                            \
        i32x4 aA0_ = *(const i32x4*)(ab_ + (wr * 2 + 0) * 2048 + lane * 16);   \
        i32x4 aA1_ = *(const i32x4*)(ab_ + (wr * 2 + 0) * 2048 + 1024 + lane * 16); \
        i32x4 aB0_ = *(const i32x4*)(ab_ + (wr * 2 + 1) * 2048 + lane * 16);   \
        i32x4 aB1_ = *(const i32x4*)(ab_ + (wr * 2 + 1) * 2048 + 1024 + lane * 16); \
        _Pragma("unroll")                                                      \
        for (int kk2_ = 0; kk2_ < 2; ++kk2_) {                                 \
            const uint32_t q0_ = (uint32_t)bv_[kk2_];                          \
            const uint32_t q1_ = (uint32_t)bv_[2 + kk2_];                      \
            i32x4 b0_, b1_;                                                    \
            _Pragma("unroll")                                                  \
            for (int i_ = 0; i_ < 4; ++i_) {                                   \
                b0_[i_] = (int)((q0_ >> (2 * i_)) & 0x03030303u);              \
                b1_[i_] = (int)((q1_ >> (2 * i_)) & 0x03030303u);              \
            }                                                                  \
            const i32x4 am0_ = kk2_ ? aA1_ : aA0_;                             \
            const i32x4 am1_ = kk2_ ? aB1_ : aB0_;                             \
            acc[0][0] = MFMA_I8(am0_, b0_, acc[0][0], 0, 0, 0);                \
            acc[0][1] = MFMA_I8(am0_, b1_, acc[0][1], 0, 0, 0);                \
            acc[1][0] = MFMA_I8(am1_, b0_, acc[1][0], 0, 0, 0);                \
            acc[1][1] = MFMA_I8(am1_, b1_, acc[1][1], 0, 0, 0);                \
        }                                                                      \
    }                                                                          \
} while (0)

// One iteration = 2 K-steps. wait(own stage T + B T retired) -> barrier
// (slot globally ready; ring slot T-1 free for overwrite) -> prefetch ->
// stage slot T+2 -> compute.
#define ITER2(T, SL, SLN, BI, BN, NW, DS, DB) do {                             \
    asm volatile("s_waitcnt vmcnt(" #NW ")" ::: "memory");                     \
    __builtin_amdgcn_s_barrier();                                              \
    __builtin_amdgcn_sched_barrier(0);                                         \
    if (DB) BLOAD2(BN, (T) + 1);                                               \
    if (DS) STAGE2(SLN, (T) + 2);                                              \
    COMP2(SL, BI);                                                             \
} while (0)

__global__ __launch_bounds__(256, 3) void bitnet_gemm(const uint8_t* __restrict__ A2,
                                                      const uint8_t* __restrict__ B3,
                                                      int* __restrict__ C) {
    const int tid  = threadIdx.x;
    const int lane = tid & 63, wave = tid >> 6;
    const int wr   = wave >> 1, wc = wave & 1;
    const int l31  = lane & 31, h = lane >> 5;

    // bijective XCD swizzle (688 = 8*86), bm fastest within an XCD chunk.
    const int bid = blockIdx.x;
    const int l   = (bid & 7) * (NBLOCKS / 8) + (bid >> 3);
    const int bm  = l & 7;       // 128-row tile 0..7
    const int bn  = l >> 3;      // 128-col tile 0..85

    __shared__ __align__(16) uint8_t As[3][16384];   // 48 KiB ring

    const uint8_t* gA = A2 + (size_t)bm * 8192 + tid * 16;
    const uint8_t* gB = B3 + (size_t)bn * 2048 + wc * 1024 + lane * 16;

    i32x16 acc[2][2] = {};
    i32x4 bb0[2], bb1[2];

    // prologue: B pair 0, slots 0 and 1 (iters 0,1 = ksteps 0..3)
    BLOAD2(0, 0);
    STAGE2(0, 0);
    STAGE2(1, 1);

#pragma unroll 1
    for (int t = 0; t < 30; t += 6) {
        ITER2(t + 0, 0, 2, 0, 1, 4, 1, 1);
        ITER2(t + 1, 1, 0, 1, 0, 4, 1, 1);
        ITER2(t + 2, 2, 1, 0, 1, 4, 1, 1);
        ITER2(t + 3, 0, 2, 1, 0, 4, 1, 1);
        ITER2(t + 4, 1, 0, 0, 1, 4, 1, 1);
        ITER2(t + 5, 2, 1, 1, 0, 4, 1, 1);
    }
    // T=30: no stage (slot 32 doesn't exist), still load B(31)
    ITER2(30, 0, 2, 0, 1, 4, 0, 1);
    // T=31: drain
    ITER2(31, 1, 0, 1, 0, 0, 0, 0);

    // C write: col = lane&31, row = (r&3) + 8*(r>>2) + 4*(lane>>5)
    const int brow = bm * 128, bcol = bn * 128;
#pragma unroll
    for (int mi = 0; mi < 2; ++mi)
#pragma unroll
        for (int ni = 0; ni < 2; ++ni) {
            const int colg = bcol + wc * 64 + ni * 32 + l31;
#pragma unroll
            for (int r = 0; r < 16; ++r) {
                const int rowin = (r & 3) + 8 * (r >> 2) + 4 * h;
                const int rowg  = brow + wr * 64 + mi * 32 + rowin;
                C[(size_t)rowg * NN + colg] = acc[mi][ni][r];
            }
        }
}

extern "C" void kernel_launch(void* const* d_in, const int* in_sizes, int n_in,
                              void* d_out, int out_size, void* d_ws, size_t ws_size,
                              hipStream_t stream) {
    const int* A32 = (const int*)d_in[0];   // [M,K] int8 values in int32
    const int* B32 = (const int*)d_in[1];   // [N,K/4] packed bytes in int32
    int* C = (int*)d_out;                   // [M,N] int32

    uint8_t* A2 = (uint8_t*)d_ws;                      // 4 MiB
    uint8_t* B3 = A2 + (size_t)MM * KK;                // 10.75 MiB

    prep_AB<<<dim3(1024 + 2752), dim3(256), 0, stream>>>(A32, B32, A2, B3);
    bitnet_gemm<<<dim3(NBLOCKS), dim3(256), 0, stream>>>(A2, B3, C);
}